// Round 13
// baseline (421.628 us; speedup 1.0000x reference)
//
#include <hip/hip_runtime.h>
#include <hip/hip_bf16.h>
#include <math.h>

#define NBLK 512
#define ROWS (NBLK / 256)
#define MAXNC 512     // supports N up to 131072 (256 nodes per coarse bucket)
#define STAGE_CAP 12512  // >= chunk = ceil(E/NBLK) 4-aligned (E=6.4M -> 12500)

// ---------------- pass A: coarse histogram per block chunk (int4 loads) ----------------
__global__ void k_hist(const int* __restrict__ dst, int* __restrict__ hist,
                       int nE, int nc, int chunk) {
    __shared__ int ch[MAXNC];
    int b = blockIdx.x, t = threadIdx.x;
    for (int i = t; i < nc; i += 256) ch[i] = 0;
    __syncthreads();
    int c0 = b * chunk, c1 = min(nE, c0 + chunk);
    if (c1 > c0) {
        int nv = (c1 - c0) >> 2;
        const int4* d4 = (const int4*)(dst + c0);
        for (int i = t; i < nv; i += 256) {
            int4 dd = d4[i];
            atomicAdd(&ch[dd.x >> 8], 1);
            atomicAdd(&ch[dd.y >> 8], 1);
            atomicAdd(&ch[dd.z >> 8], 1);
            atomicAdd(&ch[dd.w >> 8], 1);
        }
        int rem = (c1 - c0) & 3;
        if (t < rem) atomicAdd(&ch[dst[c0 + (nv << 2) + t] >> 8], 1);
    }
    __syncthreads();
    for (int i = t; i < nc; i += 256) hist[b * nc + i] = ch[i];
}

// ---------------- pass B1: per-bucket scan -> padded offT, padded & real totals ----------------
__global__ void k_scanA(const int* __restrict__ hist, int* __restrict__ offT,
                        int* __restrict__ totPad, int* __restrict__ totReal, int nc) {
    __shared__ int sums[256];
    __shared__ int red[256];
    int c = blockIdx.x, t = threadIdx.x;
    int v[ROWS], p[ROWS];
    int s = 0, sr = 0;
#pragma unroll
    for (int j = 0; j < ROWS; ++j) {
        v[j] = hist[(size_t)(t * ROWS + j) * nc + c];
        p[j] = (v[j] + 15) & ~15;
        s += p[j];
        sr += v[j];
    }
    sums[t] = s;
    red[t] = sr;
    __syncthreads();
    for (int d = 1; d < 256; d <<= 1) {
        int x = (t >= d) ? sums[t - d] : 0;
        __syncthreads();
        sums[t] += x;
        __syncthreads();
    }
    int run = sums[t] - s;
#pragma unroll
    for (int j = 0; j < ROWS; ++j) {
        offT[(size_t)c * NBLK + t * ROWS + j] = run;
        run += p[j];
    }
    if (t == 255) totPad[c] = sums[255];
    for (int d = 128; d > 0; d >>= 1) {
        if (t < d) red[t] += red[t + d];
        __syncthreads();
    }
    if (t == 0) totReal[c] = red[0];
}

// ---------------- pass B2: scan totals -> cbase (padded) and rbase (real) ----------------
__global__ void k_scanB(const int* __restrict__ totPad, const int* __restrict__ totReal,
                        int* __restrict__ cbase, int* __restrict__ rbase,
                        int* __restrict__ rowstart, int nE, int nc, int n) {
    __shared__ int sp[512];
    __shared__ int sr[512];
    int t = threadIdx.x;
    int vp = (t < nc) ? totPad[t] : 0;
    int vr = (t < nc) ? totReal[t] : 0;
    sp[t] = vp; sr[t] = vr;
    __syncthreads();
    for (int d = 1; d < 512; d <<= 1) {
        int xp = (t >= d) ? sp[t - d] : 0;
        int xr = (t >= d) ? sr[t - d] : 0;
        __syncthreads();
        sp[t] += xp; sr[t] += xr;
        __syncthreads();
    }
    if (t < nc) { cbase[t] = sp[t] - vp; rbase[t] = sr[t] - vr; }
    if (t == nc - 1) cbase[nc] = sp[t];
    if (t == 0) rowstart[n] = nE;
}

// ---------------- pass C: LDS-staged partition + full-line flush ----------------
__global__ __launch_bounds__(256, 2)
void k_fill(const int* __restrict__ src, const int* __restrict__ dst,
            const int* __restrict__ hist, const int* __restrict__ offT,
            const int* __restrict__ cbase,
            int* __restrict__ bucketed, int nE, int nc, int chunk) {
    __shared__ int stage[STAGE_CAP];
    __shared__ int sc[256];
    __shared__ int lbeg[MAXNC];
    __shared__ int lcur[MAXNC];
    int b = blockIdx.x, t = threadIdx.x;

    int v0 = (2 * t < nc) ? hist[(size_t)b * nc + 2 * t] : 0;
    int v1 = (2 * t + 1 < nc) ? hist[(size_t)b * nc + 2 * t + 1] : 0;
    int s = v0 + v1;
    sc[t] = s;
    __syncthreads();
    for (int d = 1; d < 256; d <<= 1) {
        int x = (t >= d) ? sc[t - d] : 0;
        __syncthreads();
        sc[t] += x;
        __syncthreads();
    }
    int excl = sc[t] - s;
    if (2 * t < nc) { lbeg[2 * t] = excl; lcur[2 * t] = excl; }
    if (2 * t + 1 < nc) { lbeg[2 * t + 1] = excl + v0; lcur[2 * t + 1] = excl + v0; }
    __syncthreads();

    int c0 = b * chunk, c1 = min(nE, c0 + chunk);
    if (c1 > c0) {
        int nv = (c1 - c0) >> 2;
        const int4* d4 = (const int4*)(dst + c0);
        const int4* s4 = (const int4*)(src + c0);
        for (int i = t; i < nv; i += 256) {
            int4 dd = d4[i];
            int4 ss = s4[i];
            int pos;
            pos = atomicAdd(&lcur[dd.x >> 8], 1); stage[pos] = ss.x | ((dd.x & 255) << 17);
            pos = atomicAdd(&lcur[dd.y >> 8], 1); stage[pos] = ss.y | ((dd.y & 255) << 17);
            pos = atomicAdd(&lcur[dd.z >> 8], 1); stage[pos] = ss.z | ((dd.z & 255) << 17);
            pos = atomicAdd(&lcur[dd.w >> 8], 1); stage[pos] = ss.w | ((dd.w & 255) << 17);
        }
        int rem = (c1 - c0) & 3;
        if (t < rem) {
            int e = c0 + (nv << 2) + t;
            int d = dst[e];
            int pos = atomicAdd(&lcur[d >> 8], 1);
            stage[pos] = src[e] | ((d & 255) << 17);
        }
    }
    __syncthreads();

    for (int c = t; c < nc; c += 256) {
        int lo = lbeg[c];
        int cnt = lcur[c] - lo;
        int g = cbase[c] + offT[(size_t)c * NBLK + b];
        int padded = (cnt + 15) & ~15;
        for (int i = 0; i < padded; i += 4) {
            int4 v;
            v.x = (i + 0 < cnt) ? stage[lo + i + 0] : -1;
            v.y = (i + 1 < cnt) ? stage[lo + i + 1] : -1;
            v.z = (i + 2 < cnt) ? stage[lo + i + 2] : -1;
            v.w = (i + 3 < cnt) ? stage[lo + i + 3] : -1;
            *(int4*)(bucketed + g + i) = v;
        }
    }
}

// ---------------- pass D: within-bucket sort to compact per-node CSR ----------------
__global__ void k_fine(const int* __restrict__ bucketed, const int* __restrict__ cbase,
                       const int* __restrict__ rbase,
                       int* __restrict__ csr, int* __restrict__ rowstart,
                       float* __restrict__ dinv, int n) {
    __shared__ int cnt[256];
    __shared__ int lrs[512];
    __shared__ int cur[256];
    int cb = blockIdx.x, t = threadIdx.x;  // 512 threads
    int e0 = cbase[cb], e1 = cbase[cb + 1];
    int r0 = rbase[cb];
    if (t < 256) cnt[t] = 0;
    __syncthreads();
    int nv = (e1 - e0) >> 2;
    const int4* b4 = (const int4*)(bucketed + e0);
    for (int i = t; i < nv; i += 512) {
        int4 en = b4[i];
        if (en.x >= 0) atomicAdd(&cnt[(en.x >> 17) & 255], 1);
        if (en.y >= 0) atomicAdd(&cnt[(en.y >> 17) & 255], 1);
        if (en.z >= 0) atomicAdd(&cnt[(en.z >> 17) & 255], 1);
        if (en.w >= 0) atomicAdd(&cnt[(en.w >> 17) & 255], 1);
    }
    __syncthreads();
    int my = (t < 256) ? cnt[t] : 0;
    lrs[t] = my;
    __syncthreads();
    for (int d = 1; d < 512; d <<= 1) {
        int x = (t >= d) ? lrs[t - d] : 0;
        __syncthreads();
        lrs[t] += x;
        __syncthreads();
    }
    if (t < 256) {
        int excl = lrs[t] - my;
        int node = cb * 256 + t;
        if (node < n) {
            rowstart[node] = r0 + excl;
            dinv[node] = rsqrtf((float)(my + 1));
        }
        cur[t] = r0 + excl;
    }
    __syncthreads();
    for (int i = t; i < nv; i += 512) {
        int4 en = b4[i];
        int pos;
        if (en.x >= 0) { pos = atomicAdd(&cur[(en.x >> 17) & 255], 1); csr[pos] = en.x & 0x1FFFF; }
        if (en.y >= 0) { pos = atomicAdd(&cur[(en.y >> 17) & 255], 1); csr[pos] = en.y & 0x1FFFF; }
        if (en.z >= 0) { pos = atomicAdd(&cur[(en.z >> 17) & 255], 1); csr[pos] = en.z & 0x1FFFF; }
        if (en.w >= 0) { pos = atomicAdd(&cur[(en.w >> 17) & 255], 1); csr[pos] = en.w & 0x1FFFF; }
    }
}

// ---------------- prescale: xs = dinv * x, split into 8-feature halves ----------------
__global__ void k_prescale(const float* __restrict__ x, const float* __restrict__ dinv,
                           float* __restrict__ xsA, float* __restrict__ xsB, int n) {
    int i = blockIdx.x * blockDim.x + threadIdx.x;
    if (i >= n) return;
    float di = dinv[i];
    const float4* xp = (const float4*)(x + (size_t)i * 16);
    float4 v0 = xp[0], v1 = xp[1], v2 = xp[2], v3 = xp[3];
    v0.x *= di; v0.y *= di; v0.z *= di; v0.w *= di;
    v1.x *= di; v1.y *= di; v1.z *= di; v1.w *= di;
    v2.x *= di; v2.y *= di; v2.z *= di; v2.w *= di;
    v3.x *= di; v3.y *= di; v3.z *= di; v3.w *= di;
    float4* a = (float4*)(xsA + (size_t)i * 8);
    float4* b = (float4*)(xsB + (size_t)i * 8);
    a[0] = v0; a[1] = v1;
    b[0] = v2; b[1] = v3;
}

// ---------------- agg: wave per node, 32 edge-slots x 2 lanes, 32B rows ----------------
// Gathers sum_{e in adj(i)} hhalf[src_e][0..8) into agg[i][0..8). L2-resident source
// (3.2 MB); csr via nontemporal loads to protect residency.
__global__ void k_agg(const float* __restrict__ hhalf, const int* __restrict__ csr,
                      const int* __restrict__ rowstart, float* __restrict__ agg, int n) {
    int wid = (blockIdx.x * blockDim.x + threadIdx.x) >> 6;
    if (wid >= n) return;
    int lane = threadIdx.x & 63;
    int q = lane >> 1;   // edge slot 0..31
    int c = lane & 1;    // feature quad (0: f0..3, 1: f4..7)
    int r0 = rowstart[wid], r1 = rowstart[wid + 1];
    int cnt = r1 - r0;
    const int* p = csr + r0 + q;
    int my = (cnt > q) ? ((cnt - q + 31) >> 5) : 0;

    float av[4] = {0.f, 0.f, 0.f, 0.f};
    int s0 = (my > 0) ? __builtin_nontemporal_load(p) : 0;
    int s1 = (my > 1) ? __builtin_nontemporal_load(p + 32) : 0;
    for (int t = 0; t < my; ++t) {
        int scur = s0;
        s0 = s1;
        s1 = (t + 2 < my) ? __builtin_nontemporal_load(p + (t + 2) * 32) : 0;
        float4 v = *(const float4*)(hhalf + (size_t)scur * 8 + c * 4);
        av[0] += v.x; av[1] += v.y; av[2] += v.z; av[3] += v.w;
    }
    // reduce across the 32 edge slots (lane bits 1..5)
#pragma unroll
    for (int m = 2; m <= 32; m <<= 1) {
#pragma unroll
        for (int j = 0; j < 4; ++j) av[j] += __shfl_xor(av[j], m);
    }
    if (lane < 2)
        *(float4*)(agg + (size_t)wid * 8 + c * 4) = make_float4(av[0], av[1], av[2], av[3]);
}

// ---------------- post: per-node 16x16 GEMM epilogue (4 threads/node) ----------------
// MODE 0: GCN  y = tanh((di*(agg_k + xs_k)) @ Wa + ba)        [xs = di*x]
// MODE 1: SAGE + tanh; MODE 2: SAGE plain
//   SAGE: y = (agg/max(cnt,1)) @ Wa + ba + h @ Wb; y /= max(||y||, eps)
template <int MODE>
__global__ void k_post(const float* __restrict__ aggA, const float* __restrict__ aggB,
                       const float* __restrict__ selfA, const float* __restrict__ selfB,
                       const int* __restrict__ rowstart, const float* __restrict__ dinv,
                       const float* __restrict__ Wa, const float* __restrict__ ba,
                       const float* __restrict__ Wb,
                       float* __restrict__ houtA, float* __restrict__ houtB, int n) {
    int idx = blockIdx.x * blockDim.x + threadIdx.x;
    int node = idx >> 2;
    if (node >= n) return;
    int t4 = idx & 3;
    int lane = threadIdx.x & 63;
    int lbase = lane & 60;

    const float* ap = ((t4 < 2) ? aggA : aggB) + (size_t)node * 8 + (t4 & 1) * 4;
    const float* sp = ((t4 < 2) ? selfA : selfB) + (size_t)node * 8 + (t4 & 1) * 4;
    float4 av = *(const float4*)ap;
    float4 sv = *(const float4*)sp;

    // broadcast: quad-thread g holds k = 4g..4g+3
    float a[16], s[16];
#pragma unroll
    for (int g = 0; g < 4; ++g) {
        a[g * 4 + 0] = __shfl(av.x, lbase + g);
        a[g * 4 + 1] = __shfl(av.y, lbase + g);
        a[g * 4 + 2] = __shfl(av.z, lbase + g);
        a[g * 4 + 3] = __shfl(av.w, lbase + g);
        s[g * 4 + 0] = __shfl(sv.x, lbase + g);
        s[g * 4 + 1] = __shfl(sv.y, lbase + g);
        s[g * 4 + 2] = __shfl(sv.z, lbase + g);
        s[g * 4 + 3] = __shfl(sv.w, lbase + g);
    }

    int fo = t4 * 4;
    float yv[4];
    if (MODE == 0) {
        float di = dinv[node];
#pragma unroll
        for (int k = 0; k < 16; ++k) a[k] = di * (a[k] + s[k]);
#pragma unroll
        for (int j = 0; j < 4; ++j) yv[j] = ba[fo + j];
#pragma unroll
        for (int k = 0; k < 16; ++k) {
            float4 w = *(const float4*)(Wa + k * 16 + fo);
            yv[0] += a[k] * w.x; yv[1] += a[k] * w.y;
            yv[2] += a[k] * w.z; yv[3] += a[k] * w.w;
        }
#pragma unroll
        for (int j = 0; j < 4; ++j) yv[j] = tanhf(yv[j]);
    } else {
        int cnt = rowstart[node + 1] - rowstart[node];
        float inv = 1.0f / fmaxf((float)cnt, 1.0f);
#pragma unroll
        for (int k = 0; k < 16; ++k) a[k] *= inv;
#pragma unroll
        for (int j = 0; j < 4; ++j) yv[j] = ba[fo + j];
#pragma unroll
        for (int k = 0; k < 16; ++k) {
            float4 wa = *(const float4*)(Wa + k * 16 + fo);
            float4 wb = *(const float4*)(Wb + k * 16 + fo);
            yv[0] += a[k] * wa.x + s[k] * wb.x;
            yv[1] += a[k] * wa.y + s[k] * wb.y;
            yv[2] += a[k] * wa.z + s[k] * wb.z;
            yv[3] += a[k] * wa.w + s[k] * wb.w;
        }
        float sq = yv[0] * yv[0] + yv[1] * yv[1] + yv[2] * yv[2] + yv[3] * yv[3];
        sq += __shfl_xor(sq, 1);
        sq += __shfl_xor(sq, 2);
        float nrm = fmaxf(sqrtf(sq), 1e-12f);
#pragma unroll
        for (int j = 0; j < 4; ++j) yv[j] /= nrm;
        if (MODE == 1) {
#pragma unroll
            for (int j = 0; j < 4; ++j) yv[j] = tanhf(yv[j]);
        }
    }
    float* op = ((t4 < 2) ? houtA : houtB) + (size_t)node * 8 + (t4 & 1) * 4;
    *(float4*)op = make_float4(yv[0], yv[1], yv[2], yv[3]);
}

// ---------------- Fused MLP v7: scalar-datapath W operands ----------------
#define MLP_NODES 64
__global__ __launch_bounds__(256)
void k_mlp(const float* __restrict__ h3A, const float* __restrict__ h3B,
           const float* __restrict__ W1, const float* __restrict__ b1,
           const float* __restrict__ W2, const float* __restrict__ b2,
           const float* __restrict__ W3, const float* __restrict__ b3,
           float* __restrict__ out, int n) {
    __shared__ float t1T[128][65];
    __shared__ float hpart[MLP_NODES][5];

    int t = threadIdx.x;
    int w = t >> 6;
    int l = t & 63;
    int ow = __builtin_amdgcn_readfirstlane(w * 32);
    int node0 = blockIdx.x * MLP_NODES;
    int node = node0 + l;
    int nodec = min(node, n - 1);

    float acc[32];
    {
        float h[16];
        const float4* hpa = (const float4*)(h3A + (size_t)nodec * 8);
        const float4* hpb = (const float4*)(h3B + (size_t)nodec * 8);
        float4 v0 = hpa[0], v1 = hpa[1], v2 = hpb[0], v3 = hpb[1];
        h[0] = v0.x; h[1] = v0.y; h[2] = v0.z; h[3] = v0.w;
        h[4] = v1.x; h[5] = v1.y; h[6] = v1.z; h[7] = v1.w;
        h[8] = v2.x; h[9] = v2.y; h[10] = v2.z; h[11] = v2.w;
        h[12] = v3.x; h[13] = v3.y; h[14] = v3.z; h[15] = v3.w;
        const float* bp = b1 + ow;
#pragma unroll
        for (int j = 0; j < 32; ++j) acc[j] = bp[j];
#pragma unroll
        for (int k = 0; k < 16; ++k) {
            const float* wr = W1 + k * 128 + ow;
            float hk = h[k];
#pragma unroll
            for (int j = 0; j < 32; ++j) acc[j] += hk * wr[j];
        }
#pragma unroll
        for (int j = 0; j < 32; ++j) t1T[ow + j][l] = fmaxf(acc[j], 0.f);
    }
    __syncthreads();

    {
        const float* bp = b2 + ow;
#pragma unroll
        for (int j = 0; j < 32; ++j) acc[j] = bp[j];
    }
    for (int k = 0; k < 128; ++k) {
        float tk = t1T[k][l];
        const float* wr = W2 + k * 128 + ow;
#pragma unroll
        for (int j = 0; j < 32; ++j) acc[j] += tk * wr[j];
    }

    float part = 0.f;
    {
        const float* wr = W3 + ow;
#pragma unroll
        for (int j = 0; j < 32; ++j) part += fmaxf(acc[j], 0.f) * wr[j];
    }
    hpart[l][w] = part;
    __syncthreads();
    if (w == 0 && node < n) {
        out[node] = hpart[l][0] + hpart[l][1] + hpart[l][2] + hpart[l][3] + b3[0];
    }
}

// ---------------- launch ----------------
extern "C" void kernel_launch(void* const* d_in, const int* in_sizes, int n_in,
                              void* d_out, int out_size, void* d_ws, size_t ws_size,
                              hipStream_t stream) {
    const float* x = (const float*)d_in[0];
    const int* ei = (const int*)d_in[1];
    const float* W_gcn = (const float*)d_in[2];
    const float* b_gcn = (const float*)d_in[3];
    const float* Wl1 = (const float*)d_in[4];
    const float* bl1 = (const float*)d_in[5];
    const float* Wr1 = (const float*)d_in[6];
    const float* Wl2 = (const float*)d_in[7];
    const float* bl2 = (const float*)d_in[8];
    const float* Wr2 = (const float*)d_in[9];
    const float* W1 = (const float*)d_in[10];
    const float* b1 = (const float*)d_in[11];
    const float* W2 = (const float*)d_in[12];
    const float* b2 = (const float*)d_in[13];
    const float* W3 = (const float*)d_in[14];
    const float* b3 = (const float*)d_in[15];

    const int N = in_sizes[0] / 16;
    const int E = in_sizes[1] / 2;
    const int NC = (N + 255) >> 8;
    const int chunk = (((E + NBLK - 1) / NBLK) + 3) & ~3;
    const int* src = ei;
    const int* dst = ei + E;

    char* w = (char*)d_ws;
    auto alloc = [&](size_t bytes) {
        void* p = (void*)w;
        w += (bytes + 255) & ~(size_t)255;
        return p;
    };
    int* hist = (int*)alloc((size_t)NBLK * NC * 4);
    int* offT = (int*)alloc((size_t)NBLK * NC * 4);
    int* totPad = (int*)alloc((size_t)NC * 4);
    int* totReal = (int*)alloc((size_t)NC * 4);
    int* cbase = (int*)alloc((size_t)(NC + 1) * 4);
    int* rbase = (int*)alloc((size_t)NC * 4);
    int* rowstart = (int*)alloc((size_t)(N + 1) * 4);
    float* dinv = (float*)alloc((size_t)N * 4);
    int* bucketed = (int*)alloc(((size_t)E + (size_t)NBLK * NC * 16) * 4);
    int* csr = (int*)alloc((size_t)E * 4);
    float* xsA = (float*)alloc((size_t)N * 8 * 4);
    float* xsB = (float*)alloc((size_t)N * 8 * 4);
    float* aggA = (float*)alloc((size_t)N * 8 * 4);
    float* aggB = (float*)alloc((size_t)N * 8 * 4);
    float* h1A = (float*)alloc((size_t)N * 8 * 4);
    float* h1B = (float*)alloc((size_t)N * 8 * 4);
    float* h2A = (float*)alloc((size_t)N * 8 * 4);
    float* h2B = (float*)alloc((size_t)N * 8 * 4);
    float* h3A = (float*)alloc((size_t)N * 8 * 4);
    float* h3B = (float*)alloc((size_t)N * 8 * 4);

    k_hist<<<NBLK, 256, 0, stream>>>(dst, hist, E, NC, chunk);
    k_scanA<<<NC, 256, 0, stream>>>(hist, offT, totPad, totReal, NC);
    k_scanB<<<1, 512, 0, stream>>>(totPad, totReal, cbase, rbase, rowstart, E, NC, N);
    k_fill<<<NBLK, 256, 0, stream>>>(src, dst, hist, offT, cbase, bucketed, E, NC, chunk);
    k_fine<<<NC, 512, 0, stream>>>(bucketed, cbase, rbase, csr, rowstart, dinv, N);

    int blk = 256;
    int ngrid = (N + blk - 1) / blk;
    long long agg_threads = (long long)N * 64;
    int agrid = (int)((agg_threads + blk - 1) / blk);
    int pgrid = (int)(((long long)N * 4 + blk - 1) / blk);

    k_prescale<<<ngrid, blk, 0, stream>>>(x, dinv, xsA, xsB, N);

    // GCN
    k_agg<<<agrid, blk, 0, stream>>>(xsA, csr, rowstart, aggA, N);
    k_agg<<<agrid, blk, 0, stream>>>(xsB, csr, rowstart, aggB, N);
    k_post<0><<<pgrid, blk, 0, stream>>>(aggA, aggB, xsA, xsB, rowstart, dinv,
                                         W_gcn, b_gcn, W_gcn, h1A, h1B, N);
    // SAGE 1
    k_agg<<<agrid, blk, 0, stream>>>(h1A, csr, rowstart, aggA, N);
    k_agg<<<agrid, blk, 0, stream>>>(h1B, csr, rowstart, aggB, N);
    k_post<1><<<pgrid, blk, 0, stream>>>(aggA, aggB, h1A, h1B, rowstart, dinv,
                                         Wl1, bl1, Wr1, h2A, h2B, N);
    // SAGE 2
    k_agg<<<agrid, blk, 0, stream>>>(h2A, csr, rowstart, aggA, N);
    k_agg<<<agrid, blk, 0, stream>>>(h2B, csr, rowstart, aggB, N);
    k_post<2><<<pgrid, blk, 0, stream>>>(aggA, aggB, h2A, h2B, rowstart, dinv,
                                         Wl2, bl2, Wr2, h3A, h3B, N);

    int mgrid = (N + MLP_NODES - 1) / MLP_NODES;
    k_mlp<<<mgrid, blk, 0, stream>>>(h3A, h3B, W1, b1, W2, b2, W3, b3, (float*)d_out, N);
}

// Round 14
// 332.684 us; speedup vs baseline: 1.2674x; 1.2674x over previous
//
#include <hip/hip_runtime.h>
#include <hip/hip_bf16.h>
#include <math.h>

#define NBLK 512
#define ROWS (NBLK / 256)
#define MAXNC 512     // supports N up to 131072 (256 nodes per coarse bucket)
#define STAGE_CAP 12512  // >= chunk = ceil(E/NBLK) 4-aligned (E=6.4M -> 12500)

// ---------------- pass A: coarse histogram per block chunk (int4 loads) ----------------
__global__ void k_hist(const int* __restrict__ dst, int* __restrict__ hist,
                       int nE, int nc, int chunk) {
    __shared__ int ch[MAXNC];
    int b = blockIdx.x, t = threadIdx.x;
    for (int i = t; i < nc; i += 256) ch[i] = 0;
    __syncthreads();
    int c0 = b * chunk, c1 = min(nE, c0 + chunk);
    if (c1 > c0) {
        int nv = (c1 - c0) >> 2;
        const int4* d4 = (const int4*)(dst + c0);
        for (int i = t; i < nv; i += 256) {
            int4 dd = d4[i];
            atomicAdd(&ch[dd.x >> 8], 1);
            atomicAdd(&ch[dd.y >> 8], 1);
            atomicAdd(&ch[dd.z >> 8], 1);
            atomicAdd(&ch[dd.w >> 8], 1);
        }
        int rem = (c1 - c0) & 3;
        if (t < rem) atomicAdd(&ch[dst[c0 + (nv << 2) + t] >> 8], 1);
    }
    __syncthreads();
    for (int i = t; i < nc; i += 256) hist[b * nc + i] = ch[i];
}

// ---------------- pass B1: per-bucket scan -> padded offT, padded & real totals ----------------
__global__ void k_scanA(const int* __restrict__ hist, int* __restrict__ offT,
                        int* __restrict__ totPad, int* __restrict__ totReal, int nc) {
    __shared__ int sums[256];
    __shared__ int red[256];
    int c = blockIdx.x, t = threadIdx.x;
    int v[ROWS], p[ROWS];
    int s = 0, sr = 0;
#pragma unroll
    for (int j = 0; j < ROWS; ++j) {
        v[j] = hist[(size_t)(t * ROWS + j) * nc + c];
        p[j] = (v[j] + 15) & ~15;
        s += p[j];
        sr += v[j];
    }
    sums[t] = s;
    red[t] = sr;
    __syncthreads();
    for (int d = 1; d < 256; d <<= 1) {
        int x = (t >= d) ? sums[t - d] : 0;
        __syncthreads();
        sums[t] += x;
        __syncthreads();
    }
    int run = sums[t] - s;
#pragma unroll
    for (int j = 0; j < ROWS; ++j) {
        offT[(size_t)c * NBLK + t * ROWS + j] = run;
        run += p[j];
    }
    if (t == 255) totPad[c] = sums[255];
    for (int d = 128; d > 0; d >>= 1) {
        if (t < d) red[t] += red[t + d];
        __syncthreads();
    }
    if (t == 0) totReal[c] = red[0];
}

// ---------------- pass B2: scan totals -> cbase (padded) and rbase (real) ----------------
__global__ void k_scanB(const int* __restrict__ totPad, const int* __restrict__ totReal,
                        int* __restrict__ cbase, int* __restrict__ rbase,
                        int* __restrict__ rowstart, int nE, int nc, int n) {
    __shared__ int sp[512];
    __shared__ int sr[512];
    int t = threadIdx.x;
    int vp = (t < nc) ? totPad[t] : 0;
    int vr = (t < nc) ? totReal[t] : 0;
    sp[t] = vp; sr[t] = vr;
    __syncthreads();
    for (int d = 1; d < 512; d <<= 1) {
        int xp = (t >= d) ? sp[t - d] : 0;
        int xr = (t >= d) ? sr[t - d] : 0;
        __syncthreads();
        sp[t] += xp; sr[t] += xr;
        __syncthreads();
    }
    if (t < nc) { cbase[t] = sp[t] - vp; rbase[t] = sr[t] - vr; }
    if (t == nc - 1) cbase[nc] = sp[t];
    if (t == 0) rowstart[n] = nE;
}

// ---------------- pass C: LDS-staged partition + full-line flush ----------------
__global__ __launch_bounds__(256, 2)
void k_fill(const int* __restrict__ src, const int* __restrict__ dst,
            const int* __restrict__ hist, const int* __restrict__ offT,
            const int* __restrict__ cbase,
            int* __restrict__ bucketed, int nE, int nc, int chunk) {
    __shared__ int stage[STAGE_CAP];
    __shared__ int sc[256];
    __shared__ int lbeg[MAXNC];
    __shared__ int lcur[MAXNC];
    int b = blockIdx.x, t = threadIdx.x;

    int v0 = (2 * t < nc) ? hist[(size_t)b * nc + 2 * t] : 0;
    int v1 = (2 * t + 1 < nc) ? hist[(size_t)b * nc + 2 * t + 1] : 0;
    int s = v0 + v1;
    sc[t] = s;
    __syncthreads();
    for (int d = 1; d < 256; d <<= 1) {
        int x = (t >= d) ? sc[t - d] : 0;
        __syncthreads();
        sc[t] += x;
        __syncthreads();
    }
    int excl = sc[t] - s;
    if (2 * t < nc) { lbeg[2 * t] = excl; lcur[2 * t] = excl; }
    if (2 * t + 1 < nc) { lbeg[2 * t + 1] = excl + v0; lcur[2 * t + 1] = excl + v0; }
    __syncthreads();

    int c0 = b * chunk, c1 = min(nE, c0 + chunk);
    if (c1 > c0) {
        int nv = (c1 - c0) >> 2;
        const int4* d4 = (const int4*)(dst + c0);
        const int4* s4 = (const int4*)(src + c0);
        for (int i = t; i < nv; i += 256) {
            int4 dd = d4[i];
            int4 ss = s4[i];
            int pos;
            pos = atomicAdd(&lcur[dd.x >> 8], 1); stage[pos] = ss.x | ((dd.x & 255) << 17);
            pos = atomicAdd(&lcur[dd.y >> 8], 1); stage[pos] = ss.y | ((dd.y & 255) << 17);
            pos = atomicAdd(&lcur[dd.z >> 8], 1); stage[pos] = ss.z | ((dd.z & 255) << 17);
            pos = atomicAdd(&lcur[dd.w >> 8], 1); stage[pos] = ss.w | ((dd.w & 255) << 17);
        }
        int rem = (c1 - c0) & 3;
        if (t < rem) {
            int e = c0 + (nv << 2) + t;
            int d = dst[e];
            int pos = atomicAdd(&lcur[d >> 8], 1);
            stage[pos] = src[e] | ((d & 255) << 17);
        }
    }
    __syncthreads();

    for (int c = t; c < nc; c += 256) {
        int lo = lbeg[c];
        int cnt = lcur[c] - lo;
        int g = cbase[c] + offT[(size_t)c * NBLK + b];
        int padded = (cnt + 15) & ~15;
        for (int i = 0; i < padded; i += 4) {
            int4 v;
            v.x = (i + 0 < cnt) ? stage[lo + i + 0] : -1;
            v.y = (i + 1 < cnt) ? stage[lo + i + 1] : -1;
            v.z = (i + 2 < cnt) ? stage[lo + i + 2] : -1;
            v.w = (i + 3 < cnt) ? stage[lo + i + 3] : -1;
            *(int4*)(bucketed + g + i) = v;
        }
    }
}

// ---------------- pass D: within-bucket sort to compact per-node CSR ----------------
__global__ void k_fine(const int* __restrict__ bucketed, const int* __restrict__ cbase,
                       const int* __restrict__ rbase,
                       int* __restrict__ csr, int* __restrict__ rowstart,
                       float* __restrict__ dinv, int n) {
    __shared__ int cnt[256];
    __shared__ int lrs[512];
    __shared__ int cur[256];
    int cb = blockIdx.x, t = threadIdx.x;  // 512 threads
    int e0 = cbase[cb], e1 = cbase[cb + 1];
    int r0 = rbase[cb];
    if (t < 256) cnt[t] = 0;
    __syncthreads();
    int nv = (e1 - e0) >> 2;
    const int4* b4 = (const int4*)(bucketed + e0);
    for (int i = t; i < nv; i += 512) {
        int4 en = b4[i];
        if (en.x >= 0) atomicAdd(&cnt[(en.x >> 17) & 255], 1);
        if (en.y >= 0) atomicAdd(&cnt[(en.y >> 17) & 255], 1);
        if (en.z >= 0) atomicAdd(&cnt[(en.z >> 17) & 255], 1);
        if (en.w >= 0) atomicAdd(&cnt[(en.w >> 17) & 255], 1);
    }
    __syncthreads();
    int my = (t < 256) ? cnt[t] : 0;
    lrs[t] = my;
    __syncthreads();
    for (int d = 1; d < 512; d <<= 1) {
        int x = (t >= d) ? lrs[t - d] : 0;
        __syncthreads();
        lrs[t] += x;
        __syncthreads();
    }
    if (t < 256) {
        int excl = lrs[t] - my;
        int node = cb * 256 + t;
        if (node < n) {
            rowstart[node] = r0 + excl;
            dinv[node] = rsqrtf((float)(my + 1));
        }
        cur[t] = r0 + excl;
    }
    __syncthreads();
    for (int i = t; i < nv; i += 512) {
        int4 en = b4[i];
        int pos;
        if (en.x >= 0) { pos = atomicAdd(&cur[(en.x >> 17) & 255], 1); csr[pos] = en.x & 0x1FFFF; }
        if (en.y >= 0) { pos = atomicAdd(&cur[(en.y >> 17) & 255], 1); csr[pos] = en.y & 0x1FFFF; }
        if (en.z >= 0) { pos = atomicAdd(&cur[(en.z >> 17) & 255], 1); csr[pos] = en.z & 0x1FFFF; }
        if (en.w >= 0) { pos = atomicAdd(&cur[(en.w >> 17) & 255], 1); csr[pos] = en.w & 0x1FFFF; }
    }
}

// ---------------- prescale: xs = dinv * x (GCN gather source; kills dinv[s] gather) ----------------
__global__ void k_prescale(const float* __restrict__ x, const float* __restrict__ dinv,
                           float* __restrict__ xs, int n) {
    int i = blockIdx.x * blockDim.x + threadIdx.x;
    if (i >= n) return;
    float di = dinv[i];
    const float4* xp = (const float4*)(x + (size_t)i * 16);
    float4* op = (float4*)(xs + (size_t)i * 16);
#pragma unroll
    for (int q = 0; q < 4; ++q) {
        float4 v = xp[q];
        v.x *= di; v.y *= di; v.z *= di; v.w *= di;
        op[q] = v;
    }
}

// ---------------- conv: wave/node, 16 slots x 4 lanes, batch-4 gathers (MLP depth) ----------------
// MODE 0: hin = xs (pre-scaled); y = tanh((di*(sum xs_s + xs_i)) @ Wa + ba)
// MODE 1: SAGE + tanh; MODE 2: SAGE plain
template <int MODE>
__global__ void k_conv(const float* __restrict__ hin, const int* __restrict__ csr,
                       const int* __restrict__ rowstart, const float* __restrict__ dinv,
                       const float* __restrict__ Wa, const float* __restrict__ ba,
                       const float* __restrict__ Wb,
                       float* __restrict__ hout, int n) {
    int wid = (blockIdx.x * blockDim.x + threadIdx.x) >> 6;
    if (wid >= n) return;
    int lane = threadIdx.x & 63;
    int q = lane >> 2;   // edge slot 0..15
    int c = lane & 3;    // feature quad
    int r0 = rowstart[wid], r1 = rowstart[wid + 1];
    int cnt = r1 - r0;
    const int* p = csr + r0 + q;
    int my = (cnt > q) ? ((cnt - q + 15) >> 4) : 0;

    float av[4] = {0.f, 0.f, 0.f, 0.f};
    int t = 0;
    // batch-4: 4 independent gathers in flight before first use
    for (; t + 4 <= my; t += 4) {
        int s0 = p[(t + 0) * 16];
        int s1 = p[(t + 1) * 16];
        int s2 = p[(t + 2) * 16];
        int s3 = p[(t + 3) * 16];
        float4 v0 = *(const float4*)(hin + (size_t)s0 * 16 + c * 4);
        float4 v1 = *(const float4*)(hin + (size_t)s1 * 16 + c * 4);
        float4 v2 = *(const float4*)(hin + (size_t)s2 * 16 + c * 4);
        float4 v3 = *(const float4*)(hin + (size_t)s3 * 16 + c * 4);
        av[0] += (v0.x + v1.x) + (v2.x + v3.x);
        av[1] += (v0.y + v1.y) + (v2.y + v3.y);
        av[2] += (v0.z + v1.z) + (v2.z + v3.z);
        av[3] += (v0.w + v1.w) + (v2.w + v3.w);
    }
    if (t + 2 <= my) {
        int s0 = p[(t + 0) * 16];
        int s1 = p[(t + 1) * 16];
        float4 v0 = *(const float4*)(hin + (size_t)s0 * 16 + c * 4);
        float4 v1 = *(const float4*)(hin + (size_t)s1 * 16 + c * 4);
        av[0] += v0.x + v1.x; av[1] += v0.y + v1.y;
        av[2] += v0.z + v1.z; av[3] += v0.w + v1.w;
        t += 2;
    }
    if (t < my) {
        int s0 = p[t * 16];
        float4 v0 = *(const float4*)(hin + (size_t)s0 * 16 + c * 4);
        av[0] += v0.x; av[1] += v0.y; av[2] += v0.z; av[3] += v0.w;
    }
    // reduce across the 16 edge slots (lane bits 2..5)
#pragma unroll
    for (int m = 4; m <= 32; m <<= 1) {
#pragma unroll
        for (int j = 0; j < 4; ++j) av[j] += __shfl_xor(av[j], m);
    }

    float4 hv4 = *(const float4*)(hin + (size_t)wid * 16 + c * 4);
    float hvv[4] = {hv4.x, hv4.y, hv4.z, hv4.w};

    if (MODE == 0) {
        float di = dinv[wid];
#pragma unroll
        for (int j = 0; j < 4; ++j) av[j] = di * (av[j] + hvv[j]);
    } else {
        float inv = 1.0f / fmaxf((float)cnt, 1.0f);
#pragma unroll
        for (int j = 0; j < 4; ++j) av[j] *= inv;
    }

    int fo = lane & 15;
    float y = ba[fo];
#pragma unroll
    for (int k = 0; k < 16; ++k) {
        float ak = __shfl(av[k & 3], k >> 2);
        y += ak * Wa[k * 16 + fo];
        if (MODE != 0) {
            float hk = __shfl(hvv[k & 3], k >> 2);
            y += hk * Wb[k * 16 + fo];
        }
    }
    if (MODE == 0) {
        y = tanhf(y);
    } else {
        float sq = y * y;
        sq += __shfl_xor(sq, 1);
        sq += __shfl_xor(sq, 2);
        sq += __shfl_xor(sq, 4);
        sq += __shfl_xor(sq, 8);
        float nrm = fmaxf(sqrtf(sq), 1e-12f);
        y /= nrm;
        if (MODE == 1) y = tanhf(y);
    }
    if ((lane >> 4) == 0) hout[wid * 16 + fo] = y;
}

// ---------------- Fused MLP v7: scalar-datapath W operands ----------------
#define MLP_NODES 64
__global__ __launch_bounds__(256)
void k_mlp(const float* __restrict__ h3,
           const float* __restrict__ W1, const float* __restrict__ b1,
           const float* __restrict__ W2, const float* __restrict__ b2,
           const float* __restrict__ W3, const float* __restrict__ b3,
           float* __restrict__ out, int n) {
    __shared__ float t1T[128][65];
    __shared__ float hpart[MLP_NODES][5];

    int t = threadIdx.x;
    int w = t >> 6;
    int l = t & 63;
    int ow = __builtin_amdgcn_readfirstlane(w * 32);
    int node0 = blockIdx.x * MLP_NODES;
    int node = node0 + l;
    int nodec = min(node, n - 1);

    float acc[32];
    {
        float h[16];
        const float4* hp = (const float4*)(h3 + (size_t)nodec * 16);
#pragma unroll
        for (int q = 0; q < 4; ++q) {
            float4 v = hp[q];
            h[q * 4 + 0] = v.x; h[q * 4 + 1] = v.y; h[q * 4 + 2] = v.z; h[q * 4 + 3] = v.w;
        }
        const float* bp = b1 + ow;
#pragma unroll
        for (int j = 0; j < 32; ++j) acc[j] = bp[j];
#pragma unroll
        for (int k = 0; k < 16; ++k) {
            const float* wr = W1 + k * 128 + ow;
            float hk = h[k];
#pragma unroll
            for (int j = 0; j < 32; ++j) acc[j] += hk * wr[j];
        }
#pragma unroll
        for (int j = 0; j < 32; ++j) t1T[ow + j][l] = fmaxf(acc[j], 0.f);
    }
    __syncthreads();

    {
        const float* bp = b2 + ow;
#pragma unroll
        for (int j = 0; j < 32; ++j) acc[j] = bp[j];
    }
    for (int k = 0; k < 128; ++k) {
        float tk = t1T[k][l];
        const float* wr = W2 + k * 128 + ow;
#pragma unroll
        for (int j = 0; j < 32; ++j) acc[j] += tk * wr[j];
    }

    float part = 0.f;
    {
        const float* wr = W3 + ow;
#pragma unroll
        for (int j = 0; j < 32; ++j) part += fmaxf(acc[j], 0.f) * wr[j];
    }
    hpart[l][w] = part;
    __syncthreads();
    if (w == 0 && node < n) {
        out[node] = hpart[l][0] + hpart[l][1] + hpart[l][2] + hpart[l][3] + b3[0];
    }
}

// ---------------- launch ----------------
extern "C" void kernel_launch(void* const* d_in, const int* in_sizes, int n_in,
                              void* d_out, int out_size, void* d_ws, size_t ws_size,
                              hipStream_t stream) {
    const float* x = (const float*)d_in[0];
    const int* ei = (const int*)d_in[1];
    const float* W_gcn = (const float*)d_in[2];
    const float* b_gcn = (const float*)d_in[3];
    const float* Wl1 = (const float*)d_in[4];
    const float* bl1 = (const float*)d_in[5];
    const float* Wr1 = (const float*)d_in[6];
    const float* Wl2 = (const float*)d_in[7];
    const float* bl2 = (const float*)d_in[8];
    const float* Wr2 = (const float*)d_in[9];
    const float* W1 = (const float*)d_in[10];
    const float* b1 = (const float*)d_in[11];
    const float* W2 = (const float*)d_in[12];
    const float* b2 = (const float*)d_in[13];
    const float* W3 = (const float*)d_in[14];
    const float* b3 = (const float*)d_in[15];

    const int N = in_sizes[0] / 16;
    const int E = in_sizes[1] / 2;
    const int NC = (N + 255) >> 8;
    const int chunk = (((E + NBLK - 1) / NBLK) + 3) & ~3;
    const int* src = ei;
    const int* dst = ei + E;

    char* w = (char*)d_ws;
    auto alloc = [&](size_t bytes) {
        void* p = (void*)w;
        w += (bytes + 255) & ~(size_t)255;
        return p;
    };
    int* hist = (int*)alloc((size_t)NBLK * NC * 4);
    int* offT = (int*)alloc((size_t)NBLK * NC * 4);
    int* totPad = (int*)alloc((size_t)NC * 4);
    int* totReal = (int*)alloc((size_t)NC * 4);
    int* cbase = (int*)alloc((size_t)(NC + 1) * 4);
    int* rbase = (int*)alloc((size_t)NC * 4);
    int* rowstart = (int*)alloc((size_t)(N + 1) * 4);
    float* dinv = (float*)alloc((size_t)N * 4);
    int* bucketed = (int*)alloc(((size_t)E + (size_t)NBLK * NC * 16) * 4);
    int* csr = (int*)alloc((size_t)E * 4);
    float* xs = (float*)alloc((size_t)N * 16 * 4);
    float* h1 = (float*)alloc((size_t)N * 16 * 4);
    float* h2 = (float*)alloc((size_t)N * 16 * 4);
    float* h3 = (float*)alloc((size_t)N * 16 * 4);

    k_hist<<<NBLK, 256, 0, stream>>>(dst, hist, E, NC, chunk);
    k_scanA<<<NC, 256, 0, stream>>>(hist, offT, totPad, totReal, NC);
    k_scanB<<<1, 512, 0, stream>>>(totPad, totReal, cbase, rbase, rowstart, E, NC, N);
    k_fill<<<NBLK, 256, 0, stream>>>(src, dst, hist, offT, cbase, bucketed, E, NC, chunk);
    k_fine<<<NC, 512, 0, stream>>>(bucketed, cbase, rbase, csr, rowstart, dinv, N);

    int blk = 256;
    int ngrid = (N + blk - 1) / blk;
    long long conv_threads = (long long)N * 64;
    int ggrid = (int)((conv_threads + blk - 1) / blk);

    k_prescale<<<ngrid, blk, 0, stream>>>(x, dinv, xs, N);
    k_conv<0><<<ggrid, blk, 0, stream>>>(xs, csr, rowstart, dinv, W_gcn, b_gcn, W_gcn, h1, N);
    k_conv<1><<<ggrid, blk, 0, stream>>>(h1, csr, rowstart, dinv, Wl1, bl1, Wr1, h2, N);
    k_conv<2><<<ggrid, blk, 0, stream>>>(h2, csr, rowstart, dinv, Wl2, bl2, Wr2, h3, N);

    int mgrid = (N + MLP_NODES - 1) / MLP_NODES;
    k_mlp<<<mgrid, blk, 0, stream>>>(h3, W1, b1, W2, b2, W3, b3, (float*)d_out, N);
}